// Round 8
// baseline (363.239 us; speedup 1.0000x reference)
//
#include <hip/hip_runtime.h>
#include <hip/hip_bf16.h>

#define T_TOK 4096
#define HDIM  1024
#define NEXP  8
#define IDIM  1408
#define ISDIM 2816

typedef short bf16x8 __attribute__((ext_vector_type(8)));
typedef float f32x4  __attribute__((ext_vector_type(4)));
typedef unsigned short u16;
typedef unsigned short u16x4 __attribute__((ext_vector_type(4)));
typedef unsigned short u16x8 __attribute__((ext_vector_type(8)));

typedef __attribute__((address_space(1))) const void gvoid;
typedef __attribute__((address_space(3))) void lvoid;

__device__ __forceinline__ u16 f2bf(float f) {
    union { float f; unsigned u; } c; c.f = f;
    unsigned r = (c.u + 0x7FFFu + ((c.u >> 16) & 1u)) >> 16;
    return (u16)r;
}
__device__ __forceinline__ float bf2f(u16 v) {
    union { unsigned u; float f; } c; c.u = (unsigned)v << 16; return c.f;
}
__device__ __forceinline__ void glds16(const u16* g, u16* l) {
    __builtin_amdgcn_global_load_lds((gvoid*)g, (lvoid*)l, 16, 0, 0);
}

// ---------------- routing: one wave per token (no atomics) ----------------
__global__ __launch_bounds__(256) void route_kernel(
    const float* __restrict__ X, const float* __restrict__ GW,
    const float* __restrict__ SEG,
    int* __restrict__ topk_e, float* __restrict__ topk_w,
    float* __restrict__ sgate)
{
    const int t = blockIdx.x * 4 + (threadIdx.x >> 6);
    const int lane = threadIdx.x & 63;
    float acc[NEXP];
    #pragma unroll
    for (int e = 0; e < NEXP; ++e) acc[e] = 0.f;
    float sacc = 0.f;
    const float* xr = X + (size_t)t * HDIM;
    for (int h = lane; h < HDIM; h += 64) {
        float xv = xr[h];
        f32x4 g0 = *(const f32x4*)(GW + (size_t)h * NEXP);
        f32x4 g1 = *(const f32x4*)(GW + (size_t)h * NEXP + 4);
        acc[0] += xv * g0[0]; acc[1] += xv * g0[1];
        acc[2] += xv * g0[2]; acc[3] += xv * g0[3];
        acc[4] += xv * g1[0]; acc[5] += xv * g1[1];
        acc[6] += xv * g1[2]; acc[7] += xv * g1[3];
        sacc += xv * SEG[h];
    }
    #pragma unroll
    for (int off = 32; off > 0; off >>= 1) {
        #pragma unroll
        for (int e = 0; e < NEXP; ++e) acc[e] += __shfl_down(acc[e], off);
        sacc += __shfl_down(sacc, off);
    }
    if (lane == 0) {
        int e0 = 0;
        #pragma unroll
        for (int e = 1; e < NEXP; ++e) if (acc[e] > acc[e0]) e0 = e;
        int e1 = (e0 == 0) ? 1 : 0;
        #pragma unroll
        for (int e = 0; e < NEXP; ++e)
            if (e != e0 && acc[e] > acc[e1]) e1 = e;
        float w0 = 1.f / (1.f + __expf(acc[e1] - acc[e0]));
        topk_e[t * 2]     = e0; topk_e[t * 2 + 1] = e1;
        topk_w[t * 2]     = w0; topk_w[t * 2 + 1] = 1.f - w0;
        sgate[t] = 1.f / (1.f + __expf(-sacc));
    }
}

// ---------------- histogram ----------------
__global__ __launch_bounds__(256) void hist_kernel(
    const int* __restrict__ topk_e, int* __restrict__ counts)
{
    __shared__ int h[NEXP];
    if (threadIdx.x < NEXP) h[threadIdx.x] = 0;
    __syncthreads();
    int i = blockIdx.x * 256 + threadIdx.x;
    atomicAdd(&h[topk_e[i]], 1);
    __syncthreads();
    if (threadIdx.x < NEXP) atomicAdd(&counts[threadIdx.x], h[threadIdx.x]);
}

__global__ void offsets_kernel(const int* __restrict__ counts,
                               int* __restrict__ seg_start,
                               int* __restrict__ cursors)
{
    if (threadIdx.x == 0) {
        int s = 0;
        for (int e = 0; e < NEXP; ++e) {
            seg_start[e] = s; cursors[e] = s; s += counts[e];
        }
    }
}

// ---------------- scatter ----------------
__global__ __launch_bounds__(256) void scatter_kernel(
    const int* __restrict__ topk_e,
    int* __restrict__ cursors, int* __restrict__ tok_ids,
    int* __restrict__ slot)
{
    const int i = blockIdx.x * 256 + threadIdx.x;
    const int lane = threadIdx.x & 63;
    const int e = topk_e[i];
    const unsigned long long lt = (1ull << lane) - 1ull;
    #pragma unroll
    for (int ex = 0; ex < NEXP; ++ex) {
        unsigned long long mask = __ballot(e == ex);
        if (mask == 0ull) continue;
        int cnt = __popcll(mask);
        int leader = __ffsll((long long)mask) - 1;
        int base_ = 0;
        if (lane == leader) base_ = atomicAdd(&cursors[ex], cnt);
        base_ = __shfl(base_, leader);
        if (e == ex) {
            int pos = base_ + __popcll(mask & lt);
            tok_ids[pos] = i >> 1;
            slot[i] = pos;
        }
    }
}

// ---------------- converts ----------------
__global__ __launch_bounds__(256) void cvt_x_kernel(
    const float* __restrict__ in, u16* __restrict__ out, int n)
{
    int i = (blockIdx.x * 256 + threadIdx.x) * 8;
    if (i < n) {
        f32x4 a = *(const f32x4*)(in + i);
        f32x4 b = *(const f32x4*)(in + i + 4);
        u16x8 o;
        #pragma unroll
        for (int j = 0; j < 4; ++j) { o[j] = f2bf(a[j]); o[j + 4] = f2bf(b[j]); }
        *(u16x8*)(out + i) = o;
    }
}

// fp32 [K][N] slices -> bf16 [N][K] (ilv=0) or 16-row gate/up interleave (ilv=1)
__global__ __launch_bounds__(256) void transpose_cvt(
    const float* __restrict__ in0, const float* __restrict__ in1,
    u16* __restrict__ out, int K, int N, int split, int ilv)
{
    const int z = blockIdx.z;
    const int e = (z < split) ? z : z - split;
    const float* in = (z < split) ? (in0 + (size_t)z * K * N)
                                  : (in1 + (size_t)(z - split) * K * N);
    u16* o = ilv ? (out + (size_t)e * 2 * N * K)
                 : (out + (size_t)z * N * K);
    const int radd = ilv ? ((z < split) ? 0 : 16) : 0;

    __shared__ float tile[64][65];
    const int n0 = blockIdx.x * 64, k0 = blockIdx.y * 64;
    const int tx = threadIdx.x & 15;
    const int ty = threadIdx.x >> 4;

    #pragma unroll
    for (int p = 0; p < 4; ++p) {
        int k = ty + p * 16;
        f32x4 v = *(const f32x4*)(in + (size_t)(k0 + k) * N + n0 + tx * 4);
        *(f32x4*)&tile[k][tx * 4] = v;
    }
    __syncthreads();
    #pragma unroll
    for (int p = 0; p < 4; ++p) {
        int n = ty + p * 16;
        u16x4 w;
        #pragma unroll
        for (int j = 0; j < 4; ++j) w[j] = f2bf(tile[tx * 4 + j][n]);
        int R = n0 + n;
        int orow = ilv ? (((R >> 4) * 32) + (R & 15) + radd) : R;
        *(u16x4*)(o + (size_t)orow * K + k0 + tx * 4) = w;
    }
}

// ================= 256x256xBK64 8-wave GEMM building blocks =================
// LDS layout per matrix tile: slot s (16B) holds (row=s>>3, chunk=(s&7)^(row&7)).
// Staging: thread tid, round p: row = p*64 + (tid>>3), global chunk = (tid&7)^((tid>>3)&7).
// Read: data (r, c) at u16 offset r*64 + ((c^(r&7))*8).

#define MFMA16(MB, AV, BV) \
    _Pragma("unroll") for (int m_ = 0; m_ < 4; ++m_) \
        _Pragma("unroll") for (int n_ = 0; n_ < 4; ++n_) \
            acc[(MB) + m_][n_] = __builtin_amdgcn_mfma_f32_16x16x32_bf16(AV[m_], BV[n_], acc[(MB) + m_][n_], 0, 0, 0);

#define COMP256(bufo) do { \
    bf16x8 av[4], bv[4]; \
    _Pragma("unroll") for (int m_ = 0; m_ < 4; ++m_) av[m_] = *(const bf16x8*)&As[(bufo) + aof + m_ * 1024]; \
    _Pragma("unroll") for (int n_ = 0; n_ < 4; ++n_) bv[n_] = *(const bf16x8*)&Bs[(bufo) + bof + n_ * 1024]; \
    __builtin_amdgcn_s_setprio(1); MFMA16(0, av, bv) __builtin_amdgcn_s_setprio(0); \
    _Pragma("unroll") for (int m_ = 0; m_ < 4; ++m_) av[m_] = *(const bf16x8*)&As[(bufo) + aof + (m_ + 4) * 1024]; \
    __builtin_amdgcn_s_setprio(1); MFMA16(4, av, bv) __builtin_amdgcn_s_setprio(0); \
    _Pragma("unroll") for (int m_ = 0; m_ < 4; ++m_) av[m_] = *(const bf16x8*)&As[(bufo) + (aof ^ 32) + m_ * 1024]; \
    _Pragma("unroll") for (int n_ = 0; n_ < 4; ++n_) bv[n_] = *(const bf16x8*)&Bs[(bufo) + (bof ^ 32) + n_ * 1024]; \
    __builtin_amdgcn_s_setprio(1); MFMA16(0, av, bv) __builtin_amdgcn_s_setprio(0); \
    _Pragma("unroll") for (int m_ = 0; m_ < 4; ++m_) av[m_] = *(const bf16x8*)&As[(bufo) + (aof ^ 32) + (m_ + 4) * 1024]; \
    __builtin_amdgcn_s_setprio(1); MFMA16(4, av, bv) __builtin_amdgcn_s_setprio(0); \
} while (0)

#define STAGE256() do { \
    glds16(ap0, &As[stbuf + tid * 8]); \
    glds16(ap1, &As[stbuf + 4096 + tid * 8]); \
    glds16(ap2, &As[stbuf + 8192 + tid * 8]); \
    glds16(ap3, &As[stbuf + 12288 + tid * 8]); \
    glds16(bp0, &Bs[stbuf + tid * 8]); \
    glds16(bp1, &Bs[stbuf + 4096 + tid * 8]); \
    glds16(bp2, &Bs[stbuf + 8192 + tid * 8]); \
    glds16(bp3, &Bs[stbuf + 12288 + tid * 8]); \
    ap0 += 64; ap1 += 64; ap2 += 64; ap3 += 64; \
    bp0 += 64; bp1 += 64; bp2 += 64; bp3 += 64; \
    stbuf ^= 16384; } while (0)

#define GEMM_LOOP(NT) \
    STAGE256(); STAGE256(); \
    _Pragma("unroll 1") \
    for (int t = 0; t < (NT) - 2; ++t) { \
        asm volatile("s_waitcnt vmcnt(8)" ::: "memory"); \
        __builtin_amdgcn_s_barrier(); \
        COMP256((t & 1) * 16384); \
        __builtin_amdgcn_s_barrier(); \
        STAGE256(); \
    } \
    asm volatile("s_waitcnt vmcnt(8)" ::: "memory"); \
    __builtin_amdgcn_s_barrier(); \
    COMP256(0); \
    asm volatile("s_waitcnt vmcnt(0)" ::: "memory"); \
    __builtin_amdgcn_s_barrier(); \
    COMP256(16384);

// ---------------- fused gate+up: interleaved combined weights [2N][K] ----------------
// expert: grid(8, 16, 11) e=bx, m=by, neff=bz; shared: grid(8, 2, 22) m=bx*2+by
__global__ __launch_bounds__(512, 2) void gemm_gu(
    const u16* __restrict__ A, const u16* __restrict__ Bc_, size_t b_stride,
    u16* __restrict__ Hout,
    const int* __restrict__ a_ids, const int* __restrict__ seg_start,
    const int* __restrict__ counts, int Nout)
{
    extern __shared__ u16 lds[];
    u16* As = lds;
    u16* Bs = lds + 32768;

    int e, m0, cnt, base;
    if (counts) {
        e = blockIdx.x; m0 = blockIdx.y * 256;
        cnt = counts[e]; base = seg_start[e];
    } else {
        e = 0; m0 = (blockIdx.x * gridDim.y + blockIdx.y) * 256;
        cnt = T_TOK; base = 0;
    }
    if (m0 >= cnt) return;
    const u16* Bsrc = Bc_ + (size_t)e * b_stride;
    const int K = HDIM;
    const int n0e = blockIdx.z * 256;

    const int tid = threadIdx.x;
    const int srow = tid >> 3;
    const int sw = ((tid & 7) ^ (srow & 7)) * 8;

    const u16 *ap0, *ap1, *ap2, *ap3, *bp0, *bp1, *bp2, *bp3;
    {
        int r0 = m0 + srow;       if (r0 >= cnt) r0 = cnt - 1;
        int r1 = m0 + 64 + srow;  if (r1 >= cnt) r1 = cnt - 1;
        int r2 = m0 + 128 + srow; if (r2 >= cnt) r2 = cnt - 1;
        int r3 = m0 + 192 + srow; if (r3 >= cnt) r3 = cnt - 1;
        int g0 = a_ids ? a_ids[base + r0] : (base + r0);
        int g1 = a_ids ? a_ids[base + r1] : (base + r1);
        int g2 = a_ids ? a_ids[base + r2] : (base + r2);
        int g3 = a_ids ? a_ids[base + r3] : (base + r3);
        ap0 = A + (size_t)g0 * K + sw;
        ap1 = A + (size_t)g1 * K + sw;
        ap2 = A + (size_t)g2 * K + sw;
        ap3 = A + (size_t)g3 * K + sw;
        bp0 = Bsrc + (size_t)(n0e + srow) * K + sw;
        bp1 = Bsrc + (size_t)(n0e + 64 + srow) * K + sw;
        bp2 = Bsrc + (size_t)(n0e + 128 + srow) * K + sw;
        bp3 = Bsrc + (size_t)(n0e + 192 + srow) * K + sw;
    }
    int stbuf = 0;

    f32x4 acc[8][4];
    #pragma unroll
    for (int i = 0; i < 8; ++i)
        #pragma unroll
        for (int j = 0; j < 4; ++j) acc[i][j] = (f32x4){0.f, 0.f, 0.f, 0.f};

    const int lane = tid & 63;
    const int wv = tid >> 6;
    const int wr = wv >> 2;
    const int wn = wv & 3;
    const int lrow = lane & 15;
    const int kslot = lane >> 4;
    const int aof = (wr * 128 + lrow) * 64 + ((kslot ^ (lrow & 7)) * 8);
    const int bof = (wn * 64 + lrow) * 64 + ((kslot ^ (lrow & 7)) * 8);

    GEMM_LOOP(16)   // K = 1024 = 16 x 64

    const int l4 = kslot * 4;
    #pragma unroll
    for (int mf = 0; mf < 8; ++mf)
        #pragma unroll
        for (int p = 0; p < 2; ++p) {
            f32x4 g = acc[mf][2 * p], u = acc[mf][2 * p + 1];
            int ci = blockIdx.z * 128 + (wn * 2 + p) * 16 + lrow;
            #pragma unroll
            for (int j = 0; j < 4; ++j) {
                int r = m0 + wr * 128 + mf * 16 + l4 + j;
                if (r < cnt) {
                    float hv = g[j] / (1.f + __expf(-g[j])) * u[j];
                    Hout[(size_t)(base + r) * Nout + ci] = f2bf(hv);
                }
            }
        }
}

// ---------------- down GEMM 256x256: grid(40, 16) ----------------
// zz<32: expert (e=zz&7, n=(zz>>3)*256, K=IDIM, A=Hact) -> store Dexp
// zz in [32,40): shared (idx=zz-32: n=(idx&3)*256, kc=idx>>2) -> atomicAdd Out
__global__ __launch_bounds__(512, 2) void gemm_down(
    const u16* __restrict__ AE, const u16* __restrict__ AS,
    const u16* __restrict__ WDt, const u16* __restrict__ SDt,
    float* __restrict__ DexpO, float* __restrict__ OutS,
    const int* __restrict__ seg_start, const int* __restrict__ counts)
{
    extern __shared__ u16 lds[];
    u16* As = lds;
    u16* Bs = lds + 32768;

    const int zz = blockIdx.x;
    const bool shr = (zz >= 32);
    int n0, cnt, base, kst;
    size_t koff;
    const u16 *Asrc, *Bsrc;
    if (!shr) {
        int e = zz & 7;
        n0 = (zz >> 3) * 256;
        cnt = counts[e]; base = seg_start[e];
        Asrc = AE; Bsrc = WDt + (size_t)e * (HDIM * IDIM);
        kst = IDIM; koff = 0;
    } else {
        int idx = zz - 32;
        n0 = (idx & 3) * 256;
        cnt = T_TOK; base = 0;
        Asrc = AS; Bsrc = SDt;
        kst = ISDIM; koff = (size_t)(idx >> 2) * 1408;
    }
    const int m0 = blockIdx.y * 256;
    if (m0 >= cnt) return;

    const int tid = threadIdx.x;
    const int srow = tid >> 3;
    const int sw = ((tid & 7) ^ (srow & 7)) * 8;

    const u16 *ap0, *ap1, *ap2, *ap3, *bp0, *bp1, *bp2, *bp3;
    {
        int r0 = m0 + srow;       if (r0 >= cnt) r0 = cnt - 1;
        int r1 = m0 + 64 + srow;  if (r1 >= cnt) r1 = cnt - 1;
        int r2 = m0 + 128 + srow; if (r2 >= cnt) r2 = cnt - 1;
        int r3 = m0 + 192 + srow; if (r3 >= cnt) r3 = cnt - 1;
        ap0 = Asrc + (size_t)(base + r0) * kst + koff + sw;
        ap1 = Asrc + (size_t)(base + r1) * kst + koff + sw;
        ap2 = Asrc + (size_t)(base + r2) * kst + koff + sw;
        ap3 = Asrc + (size_t)(base + r3) * kst + koff + sw;
        bp0 = Bsrc + (size_t)(n0 + srow) * kst + koff + sw;
        bp1 = Bsrc + (size_t)(n0 + 64 + srow) * kst + koff + sw;
        bp2 = Bsrc + (size_t)(n0 + 128 + srow) * kst + koff + sw;
        bp3 = Bsrc + (size_t)(n0 + 192 + srow) * kst + koff + sw;
    }
    int stbuf = 0;

    f32x4 acc[8][4];
    #pragma unroll
    for (int i = 0; i < 8; ++i)
        #pragma unroll
        for (int j = 0; j < 4; ++j) acc[i][j] = (f32x4){0.f, 0.f, 0.f, 0.f};

    const int lane = tid & 63;
    const int wv = tid >> 6;
    const int wr = wv >> 2;
    const int wn = wv & 3;
    const int lrow = lane & 15;
    const int kslot = lane >> 4;
    const int aof = (wr * 128 + lrow) * 64 + ((kslot ^ (lrow & 7)) * 8);
    const int bof = (wn * 64 + lrow) * 64 + ((kslot ^ (lrow & 7)) * 8);

    GEMM_LOOP(22)   // K-chunk = 1408 = 22 x 64

    const int l4 = kslot * 4;
    #pragma unroll
    for (int mf = 0; mf < 8; ++mf)
        #pragma unroll
        for (int nf = 0; nf < 4; ++nf)
            #pragma unroll
            for (int j = 0; j < 4; ++j) {
                int r = m0 + wr * 128 + mf * 16 + l4 + j;
                if (r < cnt) {
                    int c = n0 + wn * 64 + nf * 16 + lrow;
                    if (!shr)
                        DexpO[(size_t)(base + r) * HDIM + c] = acc[mf][nf][j];
                    else
                        atomicAdd(&OutS[(size_t)r * HDIM + c], acc[mf][nf][j]);
                }
            }
}

// ---------------- combine ----------------
__global__ __launch_bounds__(256) void combine_kernel(
    const float* __restrict__ Dexp,
    const int* __restrict__ slot, const float* __restrict__ topk_w,
    const float* __restrict__ sgate, float* __restrict__ Out)
{
    int idx = blockIdx.x * 256 + threadIdx.x;
    int t = idx >> 8;
    int c = (idx & 255) * 4;
    int s0 = slot[2 * t], s1 = slot[2 * t + 1];
    float w0 = topk_w[2 * t], w1 = topk_w[2 * t + 1], sg = sgate[t];
    f32x4 sh = *(const f32x4*)(Out + (size_t)t * HDIM + c);
    f32x4 d0 = *(const f32x4*)(Dexp + (size_t)s0 * HDIM + c);
    f32x4 d1 = *(const f32x4*)(Dexp + (size_t)s1 * HDIM + c);
    f32x4 o;
    #pragma unroll
    for (int j = 0; j < 4; ++j) o[j] = sg * sh[j] + w0 * d0[j] + w1 * d1[j];
    *(f32x4*)(Out + (size_t)t * HDIM + c) = o;
}

// ---------------- launch ----------------
extern "C" void kernel_launch(void* const* d_in, const int* in_sizes, int n_in,
                              void* d_out, int out_size, void* d_ws, size_t ws_size,
                              hipStream_t stream)
{
    const float* X   = (const float*)d_in[0];
    const float* GW  = (const float*)d_in[1];
    const float* WG  = (const float*)d_in[2];
    const float* WU  = (const float*)d_in[3];
    const float* WD  = (const float*)d_in[4];
    const float* SG  = (const float*)d_in[5];
    const float* SU  = (const float*)d_in[6];
    const float* SD  = (const float*)d_in[7];
    const float* SEG = (const float*)d_in[8];
    float* Out = (float*)d_out;

    char* ws = (char*)d_ws;
    int*   counts    = (int*)(ws + 0);
    int*   seg_start = (int*)(ws + 64);
    int*   cursors   = (int*)(ws + 128);
    int*   topk_e    = (int*)(ws + 1024);
    float* topk_w    = (float*)(ws + 1024 + 32768);
    float* sgate     = (float*)(ws + 1024 + 65536);
    int*   tok_ids   = (int*)(ws + 1024 + 65536 + 16384);
    int*   slot      = (int*)(ws + 1024 + 65536 + 16384 + 32768);

    u16* Xbf  = (u16*)(ws + 0x40000ull);     // 8.4 MB
    u16* Hact = (u16*)(ws + 0xA00000ull);    // 23.1 MB ([8192][1408])
    u16* Hs   = (u16*)(ws + 0x2200000ull);   // 23.1 MB ([4096][2816])
    u16* WGUc = (u16*)(ws + 0x3A00000ull);   // 46.1 MB (8 x interleaved [2816][1024])
    u16* WDt  = (u16*)(ws + 0x6900000ull);   // 23.1 MB (8 x [1024][1408])
    u16* SGUc = (u16*)(ws + 0x8100000ull);   // 11.5 MB (interleaved [5632][1024])
    u16* SDt  = (u16*)(ws + 0x8D00000ull);   // 5.8 MB ([1024][2816])
    // Dexp aliases WGUc (33.5 MB <= 46.1 MB); written only after gemm_gu done
    float* Dexp = (float*)(ws + 0x3A00000ull);

    hipMemsetAsync(counts, 0, 64, stream);
    hipMemsetAsync(Out, 0, (size_t)T_TOK * HDIM * sizeof(float), stream);

    // routing
    route_kernel<<<T_TOK / 4, 256, 0, stream>>>(X, GW, SEG, topk_e, topk_w, sgate);
    hist_kernel<<<(T_TOK * 2) / 256, 256, 0, stream>>>(topk_e, counts);
    offsets_kernel<<<1, 64, 0, stream>>>(counts, seg_start, cursors);
    scatter_kernel<<<(T_TOK * 2) / 256, 256, 0, stream>>>(topk_e, cursors, tok_ids, slot);

    // converts
    cvt_x_kernel<<<(T_TOK * HDIM) / (256 * 8), 256, 0, stream>>>(X, Xbf, T_TOK * HDIM);
    transpose_cvt<<<dim3(IDIM / 64, HDIM / 64, 2 * NEXP), 256, 0, stream>>>(WG, WU, WGUc, HDIM, IDIM, NEXP, 1);
    transpose_cvt<<<dim3(HDIM / 64, IDIM / 64, NEXP), 256, 0, stream>>>(WD, WD, WDt, IDIM, HDIM, NEXP, 0);
    transpose_cvt<<<dim3(ISDIM / 64, HDIM / 64, 2), 256, 0, stream>>>(SG, SU, SGUc, HDIM, ISDIM, 1, 1);
    transpose_cvt<<<dim3(HDIM / 64, ISDIM / 64, 1), 256, 0, stream>>>(SD, SD, SDt, ISDIM, HDIM, 1, 0);

    // expert gate+up: N_eff = 2816 -> 11 n-tiles
    gemm_gu<<<dim3(NEXP, 16, 11), 512, 131072, stream>>>(
        Xbf, WGUc, (size_t)2 * IDIM * HDIM, Hact,
        tok_ids, seg_start, counts, IDIM);
    // shared gate+up: N_eff = 5632 -> 22 n-tiles
    gemm_gu<<<dim3(8, 2, 22), 512, 131072, stream>>>(
        Xbf, SGUc, 0, Hs,
        nullptr, nullptr, nullptr, ISDIM);

    // merged balanced down (NT=22 both paths)
    gemm_down<<<dim3(40, 16), 512, 131072, stream>>>(
        Hact, Hs, WDt, SDt, Dexp, Out,
        seg_start, counts);

    // final combine
    combine_kernel<<<(T_TOK * HDIM / 4) / 256, 256, 0, stream>>>(
        Dexp, slot, topk_w, sgate, Out);
}

// Round 9
// 348.272 us; speedup vs baseline: 1.0430x; 1.0430x over previous
//
#include <hip/hip_runtime.h>
#include <hip/hip_bf16.h>

#define T_TOK 4096
#define HDIM  1024
#define NEXP  8
#define IDIM  1408
#define ISDIM 2816

typedef short bf16x8 __attribute__((ext_vector_type(8)));
typedef float f32x4  __attribute__((ext_vector_type(4)));
typedef unsigned short u16;
typedef unsigned short u16x4 __attribute__((ext_vector_type(4)));
typedef unsigned short u16x8 __attribute__((ext_vector_type(8)));

typedef __attribute__((address_space(1))) const void gvoid;
typedef __attribute__((address_space(3))) void lvoid;

__device__ __forceinline__ u16 f2bf(float f) {
    union { float f; unsigned u; } c; c.f = f;
    unsigned r = (c.u + 0x7FFFu + ((c.u >> 16) & 1u)) >> 16;
    return (u16)r;
}
__device__ __forceinline__ float bf2f(u16 v) {
    union { unsigned u; float f; } c; c.u = (unsigned)v << 16; return c.f;
}
__device__ __forceinline__ void glds16(const u16* g, u16* l) {
    __builtin_amdgcn_global_load_lds((gvoid*)g, (lvoid*)l, 16, 0, 0);
}

// ---------------- routing: one wave per token (no atomics) ----------------
__global__ __launch_bounds__(256) void route_kernel(
    const float* __restrict__ X, const float* __restrict__ GW,
    const float* __restrict__ SEG,
    int* __restrict__ topk_e, float* __restrict__ topk_w,
    float* __restrict__ sgate)
{
    const int t = blockIdx.x * 4 + (threadIdx.x >> 6);
    const int lane = threadIdx.x & 63;
    float acc[NEXP];
    #pragma unroll
    for (int e = 0; e < NEXP; ++e) acc[e] = 0.f;
    float sacc = 0.f;
    const float* xr = X + (size_t)t * HDIM;
    for (int h = lane; h < HDIM; h += 64) {
        float xv = xr[h];
        f32x4 g0 = *(const f32x4*)(GW + (size_t)h * NEXP);
        f32x4 g1 = *(const f32x4*)(GW + (size_t)h * NEXP + 4);
        acc[0] += xv * g0[0]; acc[1] += xv * g0[1];
        acc[2] += xv * g0[2]; acc[3] += xv * g0[3];
        acc[4] += xv * g1[0]; acc[5] += xv * g1[1];
        acc[6] += xv * g1[2]; acc[7] += xv * g1[3];
        sacc += xv * SEG[h];
    }
    #pragma unroll
    for (int off = 32; off > 0; off >>= 1) {
        #pragma unroll
        for (int e = 0; e < NEXP; ++e) acc[e] += __shfl_down(acc[e], off);
        sacc += __shfl_down(sacc, off);
    }
    if (lane == 0) {
        int e0 = 0;
        #pragma unroll
        for (int e = 1; e < NEXP; ++e) if (acc[e] > acc[e0]) e0 = e;
        int e1 = (e0 == 0) ? 1 : 0;
        #pragma unroll
        for (int e = 0; e < NEXP; ++e)
            if (e != e0 && acc[e] > acc[e1]) e1 = e;
        float w0 = 1.f / (1.f + __expf(acc[e1] - acc[e0]));
        topk_e[t * 2]     = e0; topk_e[t * 2 + 1] = e1;
        topk_w[t * 2]     = w0; topk_w[t * 2 + 1] = 1.f - w0;
        sgate[t] = 1.f / (1.f + __expf(-sacc));
    }
}

// ---------------- histogram ----------------
__global__ __launch_bounds__(256) void hist_kernel(
    const int* __restrict__ topk_e, int* __restrict__ counts)
{
    __shared__ int h[NEXP];
    if (threadIdx.x < NEXP) h[threadIdx.x] = 0;
    __syncthreads();
    int i = blockIdx.x * 256 + threadIdx.x;
    atomicAdd(&h[topk_e[i]], 1);
    __syncthreads();
    if (threadIdx.x < NEXP) atomicAdd(&counts[threadIdx.x], h[threadIdx.x]);
}

__global__ void offsets_kernel(const int* __restrict__ counts,
                               int* __restrict__ seg_start,
                               int* __restrict__ cursors)
{
    if (threadIdx.x == 0) {
        int s = 0;
        for (int e = 0; e < NEXP; ++e) {
            seg_start[e] = s; cursors[e] = s; s += counts[e];
        }
    }
}

// ---------------- scatter ----------------
__global__ __launch_bounds__(256) void scatter_kernel(
    const int* __restrict__ topk_e,
    int* __restrict__ cursors, int* __restrict__ tok_ids,
    int* __restrict__ slot)
{
    const int i = blockIdx.x * 256 + threadIdx.x;
    const int lane = threadIdx.x & 63;
    const int e = topk_e[i];
    const unsigned long long lt = (1ull << lane) - 1ull;
    #pragma unroll
    for (int ex = 0; ex < NEXP; ++ex) {
        unsigned long long mask = __ballot(e == ex);
        if (mask == 0ull) continue;
        int cnt = __popcll(mask);
        int leader = __ffsll((long long)mask) - 1;
        int base_ = 0;
        if (lane == leader) base_ = atomicAdd(&cursors[ex], cnt);
        base_ = __shfl(base_, leader);
        if (e == ex) {
            int pos = base_ + __popcll(mask & lt);
            tok_ids[pos] = i >> 1;
            slot[i] = pos;
        }
    }
}

// ---------------- converts ----------------
__global__ __launch_bounds__(256) void cvt_x_kernel(
    const float* __restrict__ in, u16* __restrict__ out, int n)
{
    int i = (blockIdx.x * 256 + threadIdx.x) * 8;
    if (i < n) {
        f32x4 a = *(const f32x4*)(in + i);
        f32x4 b = *(const f32x4*)(in + i + 4);
        u16x8 o;
        #pragma unroll
        for (int j = 0; j < 4; ++j) { o[j] = f2bf(a[j]); o[j + 4] = f2bf(b[j]); }
        *(u16x8*)(out + i) = o;
    }
}

// fp32 [K][N] slice z (from in0 if z<split else in1) -> bf16 [N][K]
__global__ __launch_bounds__(256) void transpose_cvt(
    const float* __restrict__ in0, const float* __restrict__ in1,
    u16* __restrict__ out, int K, int N, int split)
{
    const int z = blockIdx.z;
    const float* in = (z < split) ? (in0 + (size_t)z * K * N)
                                  : (in1 + (size_t)(z - split) * K * N);
    u16* o = out + (size_t)z * N * K;

    __shared__ float tile[64][65];
    const int n0 = blockIdx.x * 64, k0 = blockIdx.y * 64;
    const int tx = threadIdx.x & 15;
    const int ty = threadIdx.x >> 4;

    #pragma unroll
    for (int p = 0; p < 4; ++p) {
        int k = ty + p * 16;
        f32x4 v = *(const f32x4*)(in + (size_t)(k0 + k) * N + n0 + tx * 4);
        *(f32x4*)&tile[k][tx * 4] = v;
    }
    __syncthreads();
    #pragma unroll
    for (int p = 0; p < 4; ++p) {
        int n = ty + p * 16;
        u16x4 w;
        #pragma unroll
        for (int j = 0; j < 4; ++j) w[j] = f2bf(tile[tx * 4 + j][n]);
        *(u16x4*)(o + (size_t)(n0 + n) * K + k0 + tx * 4) = w;
    }
}

// ======= 128x128xBK32, 4-wave, ring-3 LDS, counted vmcnt(8), chunk-XOR swizzle =======
// LDS tile: row r (64B = 4 chunks of 16B); slot chunk s holds global chunk s^(r&3).
// Stage: thread tid -> LDS linear tid*16B (row tid>>2, slot tid&3), global
//        k-offset ((tid&3)^((tid>>2)&3))*8 u16.
// Read (r, kslot): u16 offset r*32 + ((kslot^(r&3))*8).

// ---------------- fused gate+up GEMM: 128M x 64N ----------------
// expert mode (counts!=null): grid(8, 32, 22): e=bx, m=by, n=bz
// shared mode (counts==null): grid(8, 4, 44): m=bx*4+by, n=bz
__global__ __launch_bounds__(256) void gemm_gu(
    const u16* __restrict__ A,
    const u16* __restrict__ Bg_, const u16* __restrict__ Bu_, size_t b_stride,
    u16* __restrict__ Hout,
    const int* __restrict__ a_ids, const int* __restrict__ seg_start,
    const int* __restrict__ counts,
    int N, int Trows)
{
    int e, m_tile, cnt, base;
    if (counts) {
        e = blockIdx.x; m_tile = blockIdx.y;
        cnt = counts[e]; base = seg_start[e];
    } else {
        e = 0; m_tile = blockIdx.x * gridDim.y + blockIdx.y;
        cnt = Trows; base = 0;
    }
    const int m0 = m_tile * 128;
    if (m0 >= cnt) return;
    const int n0 = blockIdx.z * 64;
    const u16* Bg = Bg_ + (size_t)e * b_stride;
    const u16* Bu = Bu_ + (size_t)e * b_stride;
    const int K = HDIM;   // NT = 32

    __shared__ u16 As[3 * 4096];
    __shared__ u16 Bs[3 * 4096];   // rows 0..63 gate | 64..127 up

    const int tid = threadIdx.x;
    const int srow = tid >> 2;
    const int st_k = ((tid & 3) ^ (srow & 3)) * 8;
    int ar0 = m0 + srow;       if (ar0 >= cnt) ar0 = cnt - 1;
    int ar1 = m0 + srow + 64;  if (ar1 >= cnt) ar1 = cnt - 1;
    const int ga0 = a_ids ? a_ids[base + ar0] : (base + ar0);
    const int ga1 = a_ids ? a_ids[base + ar1] : (base + ar1);
    const u16* a0 = A + (size_t)ga0 * K + st_k;
    const u16* a1 = A + (size_t)ga1 * K + st_k;
    const u16* bg = Bg + (size_t)(n0 + srow) * K + st_k;
    const u16* bu = Bu + (size_t)(n0 + srow) * K + st_k;

    f32x4 accG[4][2], accU[4][2];
    #pragma unroll
    for (int i = 0; i < 4; ++i)
        #pragma unroll
        for (int j = 0; j < 2; ++j) {
            accG[i][j] = (f32x4){0.f, 0.f, 0.f, 0.f};
            accU[i][j] = (f32x4){0.f, 0.f, 0.f, 0.f};
        }

    const int lane = tid & 63;
    const int wv = tid >> 6;
    const int wr = (wv >> 1) * 64;
    const int wc = (wv & 1) * 32;
    const int lrow = lane & 15;
    const int kslot = lane >> 4;
    const int ksw = (kslot ^ (lrow & 3)) * 8;

    int offA[4], offBg[2];
    #pragma unroll
    for (int m = 0; m < 4; ++m) offA[m] = (wr + m * 16 + lrow) * 32 + ksw;
    #pragma unroll
    for (int n = 0; n < 2; ++n) offBg[n] = (wc + n * 16 + lrow) * 32 + ksw;

#define STAGE_GU(ps) do { \
    glds16(a0, &As[(ps) + tid * 8]); \
    glds16(a1, &As[(ps) + 2048 + tid * 8]); \
    glds16(bg, &Bs[(ps) + tid * 8]); \
    glds16(bu, &Bs[(ps) + 2048 + tid * 8]); \
    a0 += 32; a1 += 32; bg += 32; bu += 32; } while (0)

#define COMPUTE_GU(ps) do { \
    bf16x8 af[4], bgf[2], bux[2]; \
    _Pragma("unroll") for (int m = 0; m < 4; ++m) af[m] = *(const bf16x8*)&As[(ps) + offA[m]]; \
    _Pragma("unroll") for (int n = 0; n < 2; ++n) { \
        bgf[n] = *(const bf16x8*)&Bs[(ps) + offBg[n]]; \
        bux[n] = *(const bf16x8*)&Bs[(ps) + offBg[n] + 2048]; } \
    _Pragma("unroll") for (int m = 0; m < 4; ++m) \
        _Pragma("unroll") for (int n = 0; n < 2; ++n) { \
            accG[m][n] = __builtin_amdgcn_mfma_f32_16x16x32_bf16(af[m], bgf[n], accG[m][n], 0, 0, 0); \
            accU[m][n] = __builtin_amdgcn_mfma_f32_16x16x32_bf16(af[m], bux[n], accU[m][n], 0, 0, 0); } \
    } while (0)

    STAGE_GU(0); STAGE_GU(4096); STAGE_GU(8192);
    #pragma unroll 1
    for (int t = 0; t < 32 - 3; ++t) {
        asm volatile("s_waitcnt vmcnt(8)" ::: "memory");
        __builtin_amdgcn_s_barrier();
        const int ps = (t % 3) * 4096;
        COMPUTE_GU(ps);
        __builtin_amdgcn_s_barrier();
        STAGE_GU(ps);
    }
    // tiles NT-3, NT-2, NT-1 in flight; 32 % 3 == 2
    asm volatile("s_waitcnt vmcnt(8)" ::: "memory");
    __builtin_amdgcn_s_barrier();
    COMPUTE_GU(8192);    // (32-3)%3 = 2
    asm volatile("s_waitcnt vmcnt(4)" ::: "memory");
    __builtin_amdgcn_s_barrier();
    COMPUTE_GU(0);       // (32-2)%3 = 0
    asm volatile("s_waitcnt vmcnt(0)" ::: "memory");
    __builtin_amdgcn_s_barrier();
    COMPUTE_GU(4096);    // (32-1)%3 = 1

    const int l4 = kslot * 4;
    #pragma unroll
    for (int m = 0; m < 4; ++m)
        #pragma unroll
        for (int n = 0; n < 2; ++n)
            #pragma unroll
            for (int j = 0; j < 4; ++j) {
                int r = wr + m * 16 + l4 + j;
                if (m0 + r < cnt) {
                    int c = n0 + wc + n * 16 + lrow;
                    float g = accG[m][n][j], u = accU[m][n][j];
                    float hv = g / (1.f + __expf(-g)) * u;
                    Hout[(size_t)(base + m0 + r) * N + c] = f2bf(hv);
                }
            }
}

// ---------------- down GEMM: 128x128, ring-3, balanced NT=44 ----------------
// zz < 64: expert (e=zz&7, n=(zz>>3)*128, A=Hact) -> store Dexp
// zz in [64,80): shared k-chunk (idx=zz-64: n=(idx&7)*128, kc=idx>>3) -> atomicAdd Out
__global__ __launch_bounds__(256) void gemm_down(
    const u16* __restrict__ AE, const u16* __restrict__ AS,
    const u16* __restrict__ WDt, const u16* __restrict__ SDt,
    float* __restrict__ DexpO, float* __restrict__ OutS,
    const int* __restrict__ seg_start, const int* __restrict__ counts)
{
    const int zz = blockIdx.x;
    const bool shr = (zz >= 64);
    int n0, cnt, base, kstride;
    size_t koff;
    const u16 *Ab, *Be;
    if (!shr) {
        int e = zz & 7;
        n0 = (zz >> 3) * 128;
        cnt = counts[e]; base = seg_start[e];
        Ab = AE; Be = WDt + (size_t)e * (HDIM * IDIM);
        kstride = IDIM; koff = 0;
    } else {
        int idx = zz - 64;
        n0 = (idx & 7) * 128;
        cnt = T_TOK; base = 0;
        Ab = AS; Be = SDt;
        kstride = ISDIM; koff = (size_t)(idx >> 3) * 1408;
    }
    const int m0 = blockIdx.y * 128;
    if (m0 >= cnt) return;

    __shared__ u16 As[3 * 4096];
    __shared__ u16 Bs[3 * 4096];

    const int tid = threadIdx.x;
    const int srow = tid >> 2;
    const int st_k = ((tid & 3) ^ (srow & 3)) * 8;
    int ar0 = m0 + srow;       if (ar0 >= cnt) ar0 = cnt - 1;
    int ar1 = m0 + srow + 64;  if (ar1 >= cnt) ar1 = cnt - 1;
    const u16* a0 = Ab + (size_t)(base + ar0) * kstride + koff + st_k;
    const u16* a1 = Ab + (size_t)(base + ar1) * kstride + koff + st_k;
    const u16* b0 = Be + (size_t)(n0 + srow) * kstride + koff + st_k;
    const u16* b1 = Be + (size_t)(n0 + srow + 64) * kstride + koff + st_k;

    f32x4 acc[4][4];
    #pragma unroll
    for (int i = 0; i < 4; ++i)
        #pragma unroll
        for (int j = 0; j < 4; ++j) acc[i][j] = (f32x4){0.f, 0.f, 0.f, 0.f};

    const int lane = tid & 63;
    const int wv = tid >> 6;
    const int wr = (wv >> 1) * 64;
    const int wc = (wv & 1) * 64;
    const int lrow = lane & 15;
    const int kslot = lane >> 4;
    const int ksw = (kslot ^ (lrow & 3)) * 8;

    int offA[4], offB[4];
    #pragma unroll
    for (int m = 0; m < 4; ++m) offA[m] = (wr + m * 16 + lrow) * 32 + ksw;
    #pragma unroll
    for (int n = 0; n < 4; ++n) offB[n] = (wc + n * 16 + lrow) * 32 + ksw;

#define STAGE_DN(ps) do { \
    glds16(a0, &As[(ps) + tid * 8]); \
    glds16(a1, &As[(ps) + 2048 + tid * 8]); \
    glds16(b0, &Bs[(ps) + tid * 8]); \
    glds16(b1, &Bs[(ps) + 2048 + tid * 8]); \
    a0 += 32; a1 += 32; b0 += 32; b1 += 32; } while (0)

#define COMPUTE_DN(ps) do { \
    bf16x8 af[4], bff[4]; \
    _Pragma("unroll") for (int m = 0; m < 4; ++m) af[m] = *(const bf16x8*)&As[(ps) + offA[m]]; \
    _Pragma("unroll") for (int n = 0; n < 4; ++n) bff[n] = *(const bf16x8*)&Bs[(ps) + offB[n]]; \
    _Pragma("unroll") for (int m = 0; m < 4; ++m) \
        _Pragma("unroll") for (int n = 0; n < 4; ++n) \
            acc[m][n] = __builtin_amdgcn_mfma_f32_16x16x32_bf16(af[m], bff[n], acc[m][n], 0, 0, 0); \
    } while (0)

    STAGE_DN(0); STAGE_DN(4096); STAGE_DN(8192);
    #pragma unroll 1
    for (int t = 0; t < 44 - 3; ++t) {
        asm volatile("s_waitcnt vmcnt(8)" ::: "memory");
        __builtin_amdgcn_s_barrier();
        const int ps = (t % 3) * 4096;
        COMPUTE_DN(ps);
        __builtin_amdgcn_s_barrier();
        STAGE_DN(ps);
    }
    // 44 % 3 == 2: same tail residues as NT=32
    asm volatile("s_waitcnt vmcnt(8)" ::: "memory");
    __builtin_amdgcn_s_barrier();
    COMPUTE_DN(8192);    // (44-3)%3 = 2
    asm volatile("s_waitcnt vmcnt(4)" ::: "memory");
    __builtin_amdgcn_s_barrier();
    COMPUTE_DN(0);       // (44-2)%3 = 0
    asm volatile("s_waitcnt vmcnt(0)" ::: "memory");
    __builtin_amdgcn_s_barrier();
    COMPUTE_DN(4096);    // (44-1)%3 = 1

    const int l4 = kslot * 4;
    #pragma unroll
    for (int m = 0; m < 4; ++m)
        #pragma unroll
        for (int n = 0; n < 4; ++n)
            #pragma unroll
            for (int j = 0; j < 4; ++j) {
                int r = wr + m * 16 + l4 + j;
                if (m0 + r < cnt) {
                    int c = n0 + wc + n * 16 + lrow;
                    if (!shr)
                        DexpO[(size_t)(base + m0 + r) * HDIM + c] = acc[m][n][j];
                    else
                        atomicAdd(&OutS[(size_t)(m0 + r) * HDIM + c], acc[m][n][j]);
                }
            }
}

// ---------------- combine: out = sgate*out + w0*Dexp[s0] + w1*Dexp[s1] ----------------
__global__ __launch_bounds__(256) void combine_kernel(
    const float* __restrict__ Dexp,
    const int* __restrict__ slot, const float* __restrict__ topk_w,
    const float* __restrict__ sgate, float* __restrict__ Out)
{
    int idx = blockIdx.x * 256 + threadIdx.x;
    int t = idx >> 8;
    int c = (idx & 255) * 4;
    int s0 = slot[2 * t], s1 = slot[2 * t + 1];
    float w0 = topk_w[2 * t], w1 = topk_w[2 * t + 1], sg = sgate[t];
    f32x4 sh = *(const f32x4*)(Out + (size_t)t * HDIM + c);
    f32x4 d0 = *(const f32x4*)(Dexp + (size_t)s0 * HDIM + c);
    f32x4 d1 = *(const f32x4*)(Dexp + (size_t)s1 * HDIM + c);
    f32x4 o;
    #pragma unroll
    for (int j = 0; j < 4; ++j) o[j] = sg * sh[j] + w0 * d0[j] + w1 * d1[j];
    *(f32x4*)(Out + (size_t)t * HDIM + c) = o;
}

// ---------------- launch ----------------
extern "C" void kernel_launch(void* const* d_in, const int* in_sizes, int n_in,
                              void* d_out, int out_size, void* d_ws, size_t ws_size,
                              hipStream_t stream)
{
    const float* X   = (const float*)d_in[0];
    const float* GW  = (const float*)d_in[1];
    const float* WG  = (const float*)d_in[2];
    const float* WU  = (const float*)d_in[3];
    const float* WD  = (const float*)d_in[4];
    const float* SG  = (const float*)d_in[5];
    const float* SU  = (const float*)d_in[6];
    const float* SD  = (const float*)d_in[7];
    const float* SEG = (const float*)d_in[8];
    float* Out = (float*)d_out;

    char* ws = (char*)d_ws;
    int*   counts    = (int*)(ws + 0);
    int*   seg_start = (int*)(ws + 64);
    int*   cursors   = (int*)(ws + 128);
    int*   topk_e    = (int*)(ws + 1024);
    float* topk_w    = (float*)(ws + 1024 + 32768);
    float* sgate     = (float*)(ws + 1024 + 65536);
    int*   tok_ids   = (int*)(ws + 1024 + 65536 + 16384);
    int*   slot      = (int*)(ws + 1024 + 65536 + 16384 + 32768);

    u16* Xbf  = (u16*)(ws + 0x40000ull);     // 8.4 MB
    u16* Hact = (u16*)(ws + 0xA00000ull);    // 23.1 MB ([8192][1408])
    u16* Hs   = (u16*)(ws + 0x2200000ull);   // 23.1 MB ([4096][2816])
    u16* WGUt = (u16*)(ws + 0x3A00000ull);   // 46.1 MB (8x[I][H] gate, then 8x[I][H] up)
    u16* WDt  = (u16*)(ws + 0x6900000ull);   // 23.1 MB (8x[H][I])
    u16* SGUt = (u16*)(ws + 0x8100000ull);   // 11.5 MB ([IS][H] gate, up)
    u16* SDt  = (u16*)(ws + 0x8D00000ull);   // 5.8 MB ([H][IS])
    u16* WGt = WGUt;
    u16* WUt = WGUt + (size_t)NEXP * IDIM * HDIM;
    u16* SGt = SGUt;
    u16* SUt = SGUt + (size_t)ISDIM * HDIM;
    // Dexp aliases WGUt (33.5 MB <= 46.1 MB); written only after gemm_gu done
    float* Dexp = (float*)(ws + 0x3A00000ull);

    hipMemsetAsync(counts, 0, 64, stream);
    hipMemsetAsync(Out, 0, (size_t)T_TOK * HDIM * sizeof(float), stream);

    // routing
    route_kernel<<<T_TOK / 4, 256, 0, stream>>>(X, GW, SEG, topk_e, topk_w, sgate);
    hist_kernel<<<(T_TOK * 2) / 256, 256, 0, stream>>>(topk_e, counts);
    offsets_kernel<<<1, 64, 0, stream>>>(counts, seg_start, cursors);
    scatter_kernel<<<(T_TOK * 2) / 256, 256, 0, stream>>>(topk_e, cursors, tok_ids, slot);

    // converts
    cvt_x_kernel<<<(T_TOK * HDIM) / (256 * 8), 256, 0, stream>>>(X, Xbf, T_TOK * HDIM);
    transpose_cvt<<<dim3(IDIM / 64, HDIM / 64, 2 * NEXP), 256, 0, stream>>>(WG, WU, WGUt, HDIM, IDIM, NEXP);
    transpose_cvt<<<dim3(HDIM / 64, IDIM / 64, NEXP), 256, 0, stream>>>(WD, WD, WDt, IDIM, HDIM, NEXP);
    transpose_cvt<<<dim3(ISDIM / 64, HDIM / 64, 2), 256, 0, stream>>>(SG, SU, SGUt, HDIM, ISDIM, 1);
    transpose_cvt<<<dim3(HDIM / 64, ISDIM / 64, 1), 256, 0, stream>>>(SD, SD, SDt, ISDIM, HDIM, 1);

    // expert gate+up (XCD-affine: blockIdx.x = expert, n-tile outermost)
    gemm_gu<<<dim3(NEXP, T_TOK / 128, IDIM / 64), 256, 0, stream>>>(
        Xbf, WGt, WUt, (size_t)IDIM * HDIM, Hact,
        tok_ids, seg_start, counts, IDIM, 0);
    // shared gate+up
    gemm_gu<<<dim3(8, T_TOK / 128 / 8, ISDIM / 64), 256, 0, stream>>>(
        Xbf, SGt, SUt, 0, Hs,
        nullptr, nullptr, nullptr, ISDIM, T_TOK);

    // merged balanced down (NT=44 both paths)
    gemm_down<<<dim3(80, T_TOK / 128), 256, 0, stream>>>(
        Hact, Hs, WDt, SDt, Dexp, Out,
        seg_start, counts);

    // final combine
    combine_kernel<<<(T_TOK * HDIM / 4) / 256, 256, 0, stream>>>(
        Dexp, slot, topk_w, sgate, Out);
}